// Round 1
// 187.379 us; speedup vs baseline: 1.0280x; 1.0280x over previous
//
#include <hip/hip_runtime.h>
#include <math.h>

#define B 32
#define Q 10000
#define C 80
#define TOPK 200

// ---------------------------------------------------------------------------
// Fast double-precision exp for x in [-40, 0]  (identical bits to R2 version)
// ---------------------------------------------------------------------------
__device__ __forceinline__ double fexp(double x) {
    const double L2E   = 1.4426950408889634;      // log2(e)
    const double SHIFT = 6755399441055744.0;      // 1.5 * 2^52
    const double LN2   = 0.6931471805599453;

    double y = x * L2E;
    double t = y + SHIFT;
    union { double d; unsigned long long u; } cv;
    cv.d = t;
    int n = (int)(unsigned int)cv.u;              // low 32 bits = rint(y)
    double f = y - (t - SHIFT);                   // f in [-0.5, 0.5]
    double r = f * LN2;

    double p = 2.755731922398589e-06;             // 1/9!
    p = fma(p, r, 2.4801587301587302e-05);
    p = fma(p, r, 1.984126984126984e-04);
    p = fma(p, r, 1.3888888888888889e-03);
    p = fma(p, r, 8.333333333333333e-03);
    p = fma(p, r, 4.1666666666666664e-02);
    p = fma(p, r, 1.6666666666666666e-01);
    p = fma(p, r, 0.5);
    p = fma(p, r, 1.0);
    p = fma(p, r, 1.0);

    cv.d = p;
    cv.u += ((unsigned long long)(long long)n) << 52;
    return cv.d;
}

// ---------------------------------------------------------------------------
// Kernel 1 (UNCHANGED): 64-thread block stages 64 rows (20.25 KB LDS, stride
// 81 dwords -> conflict-free reads) via fully COALESCED dwordx4 global loads,
// then thread t computes row t from LDS. Numerics bit-identical to R2.
// ---------------------------------------------------------------------------
__global__ __launch_bounds__(64) void score_kernel(
    const float* __restrict__ logits,
    unsigned long long* __restrict__ keys,
    int* __restrict__ cls_out)
{
    __shared__ float sb[64 * 81];
    const int t = threadIdx.x;                       // 0..63
    const int rowBase = blockIdx.x * 64;
    const float4* src = (const float4*)(logits + (long long)rowBase * C);

#pragma unroll
    for (int i = 0; i < 20; ++i) {
        int g = i * 64 + t;                          // float4 index in 1280-chunk
        float4 v = src[g];                           // coalesced: lane-contiguous
        int r = g / 20;
        int c = (g % 20) * 4;
        float* d = &sb[r * 81 + c];
        d[0] = v.x; d[1] = v.y; d[2] = v.z; d[3] = v.w;
    }
    __syncthreads();

    const float* row = &sb[t * 81];                  // banks 17*t mod 32: conflict-free

    float m = -INFINITY; int idx = 0;
#pragma unroll 8
    for (int j = 0; j < 80; ++j) {
        float v = row[j];
        if (v > m) { m = v; idx = j; }               // strict >: first occurrence
    }

    const double md = (double)m;
    double s = 0.0;
#pragma unroll 8
    for (int j = 0; j < 80; ++j)
        s += fexp((double)row[j] - md);              // sequential order == R2

    float sumf  = (float)s;
    float score = 1.0f / sumf;
    unsigned int sbits = __float_as_uint(score);
    int grow = rowBase + t;
    unsigned int q = (unsigned)(grow % Q);
    keys[grow]    = ((unsigned long long)sbits << 32) |
                    (unsigned long long)(0xFFFFFFFFu - q);
    cls_out[grow] = idx;
}

// ---------------------------------------------------------------------------
// Kernel 2 v4: one block (1024 threads) per batch.
//   keys -> registers (single global pass)
//   13-bit histogram -> wave-0 threshold scan
//   11-bit REFINEMENT histogram on boundary bucket -> wave-0 scan
//     (count now ~200-210 instead of 300-600)
//   ballot-aggregated collect
//   ALL-PAIRS RANK SCATTER (replaces bitonic sort: keys unique -> rank is a
//     perfect sorting permutation; ~count broadcast LDS reads, 1 barrier)
//   sup bitmatrix -> register-resident wave-parallel greedy scan -> compaction
// ---------------------------------------------------------------------------
__global__ __launch_bounds__(1024) void nms_kernel(
    const unsigned long long* __restrict__ keys,
    const int*   __restrict__ classes,
    const float* __restrict__ seg,
    int*         __restrict__ out)
{
    __shared__ unsigned int        hist[2048];
    __shared__ unsigned long long  skey[2048];      // collected candidates
    __shared__ unsigned long long  skey2[TOPK];     // rank-scattered top-200
    __shared__ int   s_count;
    __shared__ unsigned int s_tb, s_acc, s_t2;
    __shared__ int   cidx[TOPK];
    __shared__ int   ccls[TOPK];
    __shared__ float cx1[TOPK], cx2[TOPK];
    __shared__ unsigned long long sup[TOPK][4];
    __shared__ int   keepArr[TOPK];
    __shared__ int   s_keepCount;

    const int b   = blockIdx.x;
    const int tid = threadIdx.x;
    const unsigned long long* bk = keys + (long long)b * Q;

    // ---- single global pass: keys into registers (10 per thread) ----
    unsigned long long kreg[10];
#pragma unroll
    for (int r = 0; r < 10; ++r) {
        int i = r * 1024 + tid;
        kreg[r] = (i < Q) ? bk[i] : 0ull;
    }

    for (int i = tid; i < 2048; i += 1024) hist[i] = 0;
    if (tid == 0) s_count = 0;
    __syncthreads();

    // ---- histogram of top 13 bits of key (== top 13 bits of score) ----
#pragma unroll
    for (int r = 0; r < 10; ++r) {
        if (r * 1024 + tid < Q)
            atomicAdd(&hist[(unsigned int)(kreg[r] >> 51)], 1u);
    }
    __syncthreads();

    // ---- level-1 threshold: wave-0 two-level suffix scan ----
    if (tid < 64) {
        int cs = 0;
#pragma unroll
        for (int k = 0; k < 32; ++k) cs += (int)hist[tid * 32 + k];
        int S = cs;
#pragma unroll
        for (int off = 1; off < 64; off <<= 1) {
            int o = __shfl_down(S, off, 64);
            if (tid + off < 64) S += o;
        }
        unsigned long long bal = __ballot(S >= TOPK);
        int L = 63 - __clzll(bal);
        int accBase = (L < 63) ? __shfl(S, L + 1, 64) : 0;

        int h = (tid < 32) ? (int)hist[L * 32 + tid] : 0;
        int T = h;
#pragma unroll
        for (int off = 1; off < 32; off <<= 1) {
            int o = __shfl_down(T, off, 64);
            if (tid + off < 32) T += o;
        }
        unsigned long long bal2 = __ballot((tid < 32) && (accBase + T >= TOPK));
        int k2 = 63 - __clzll(bal2);
        // suffix strictly above the threshold bucket:
        int accAbove = (k2 < 31) ? (accBase + __shfl(T, k2 + 1, 64)) : accBase;
        if (tid == 0) { s_tb = (unsigned)(L * 32 + k2); s_acc = (unsigned)accAbove; }
    }
    __syncthreads();
    const unsigned int tb  = s_tb;
    const int accAbove     = (int)s_acc;

    // ---- level-2 refinement: histogram next 11 bits within boundary bucket ----
    for (int i = tid; i < 2048; i += 1024) hist[i] = 0;
    __syncthreads();
#pragma unroll
    for (int r = 0; r < 10; ++r) {
        if (r * 1024 + tid < Q) {
            unsigned long long k = kreg[r];
            if ((unsigned int)(k >> 51) == tb)
                atomicAdd(&hist[(unsigned int)(k >> 40) & 0x7FFu], 1u);
        }
    }
    __syncthreads();

    if (tid < 64) {
        const int target2 = TOPK - accAbove;          // >= 1 by construction
        int cs = 0;
#pragma unroll
        for (int k = 0; k < 32; ++k) cs += (int)hist[tid * 32 + k];
        int S = cs;
#pragma unroll
        for (int off = 1; off < 64; off <<= 1) {
            int o = __shfl_down(S, off, 64);
            if (tid + off < 64) S += o;
        }
        unsigned long long bal = __ballot(S >= target2);
        int L = 63 - __clzll(bal);
        int accBase = (L < 63) ? __shfl(S, L + 1, 64) : 0;

        int h = (tid < 32) ? (int)hist[L * 32 + tid] : 0;
        int T = h;
#pragma unroll
        for (int off = 1; off < 32; off <<= 1) {
            int o = __shfl_down(T, off, 64);
            if (tid + off < 32) T += o;
        }
        unsigned long long bal2 = __ballot((tid < 32) && (accBase + T >= target2));
        int k2 = 63 - __clzll(bal2);
        if (tid == 0) s_t2 = (unsigned)(L * 32 + k2);
    }
    __syncthreads();
    const unsigned int t2 = s_t2;

    // ---- collect candidates passing refined threshold (ballot-aggregated) ----
#pragma unroll
    for (int r = 0; r < 10; ++r) {
        int i = r * 1024 + tid;
        unsigned long long k = kreg[r];
        unsigned int b13 = (unsigned int)(k >> 51);
        bool pred = (i < Q) &&
                    ((b13 > tb) ||
                     (b13 == tb && (((unsigned int)(k >> 40)) & 0x7FFu) >= t2));
        unsigned long long mask = __ballot(pred);
        int lane = tid & 63;
        int base;
        if (lane == 0) base = atomicAdd(&s_count, __popcll(mask));
        base = __shfl(base, 0, 64);
        if (pred) {
            int pos = base + __popcll(mask & ((1ull << lane) - 1ull));
            if (pos < 2048) skey[pos] = k;
        }
    }
    __syncthreads();

    const int count = min(s_count, 2048);             // typically ~200-210

    // ---- all-pairs rank scatter (keys unique -> exact descending sort) ----
    for (int i = tid; i < count; i += 1024) {
        unsigned long long ki = skey[i];
        int rank = 0;
        for (int j = 0; j < count; ++j)               // LDS broadcast reads
            rank += (skey[j] > ki) ? 1 : 0;
        if (rank < TOPK) skey2[rank] = ki;            // count >= TOPK guaranteed
    }
    __syncthreads();

    // ---- gather top-200 candidate metadata ----
    if (tid < TOPK) {
        unsigned long long k = skey2[tid];
        int q = (int)(0xFFFFFFFFu - (unsigned int)k);
        cidx[tid] = q;
        ccls[tid] = classes[b * Q + q];
        cx1[tid]  = seg[((long long)b * Q + q) * 2 + 0];
        cx2[tid]  = seg[((long long)b * Q + q) * 2 + 1];
    }
    __syncthreads();

    // ---- suppression bitmatrix: sup[i][w] bit bb -> j = w*64+bb suppressed by i
    for (int w2 = tid; w2 < TOPK * 4; w2 += 1024) {
        int i  = w2 >> 2, ww = w2 & 3;
        int jb = ww * 64;
        float x1 = cx1[i], x2 = cx2[i];
        int   ci = ccls[i];
        unsigned long long bits = 0ull;
        for (int bb = 0; bb < 64; ++bb) {
            int j = jb + bb;
            if (j < TOPK && j > i) {
                float inter = fminf(x2, cx2[j]) - fmaxf(x1, cx1[j]);
                if (inter > 0.0f && ccls[j] == ci)
                    bits |= (1ull << bb);
            }
        }
        sup[i][ww] = bits;
    }
    __syncthreads();

    // ---- greedy scan, wave-parallel: sup matrix register-resident in wave 0.
    // word (p,w) = p*4+w lives at reg g = p/16, lane 4*(p%16)+w.
    if (tid < 64) {
        unsigned long long w[13];
#pragma unroll
        for (int r = 0; r < 13; ++r) {
            int wg = r * 64 + tid;
            w[r] = (wg < TOPK * 4) ? sup[wg >> 2][wg & 3] : 0ull;
        }
        unsigned long long act[4]  = { ~0ull, ~0ull, ~0ull, ~0ull };
        unsigned long long kept[4] = { 0ull, 0ull, 0ull, 0ull };
#pragma unroll
        for (int g = 0; g < 13; ++g) {
#pragma unroll
            for (int s2 = 0; s2 < 16; ++s2) {
                const int p = g * 16 + s2;
                if (p >= TOPK) break;
                if ((act[p >> 6] >> (p & 63)) & 1ull) {   // replicated -> uniform
                    kept[p >> 6] |= 1ull << (p & 63);
                    unsigned long long s0 = __shfl(w[g], 4 * s2 + 0, 64);
                    unsigned long long s1 = __shfl(w[g], 4 * s2 + 1, 64);
                    unsigned long long sv = __shfl(w[g], 4 * s2 + 2, 64);
                    unsigned long long s3 = __shfl(w[g], 4 * s2 + 3, 64);
                    act[0] &= ~s0; act[1] &= ~s1; act[2] &= ~sv; act[3] &= ~s3;
                }
            }
        }
        // parallel compaction of the keep list
        int base0 = 0;
#pragma unroll
        for (int r = 0; r < 4; ++r) {
            int p = r * 64 + tid;
            if (p < TOPK && ((kept[r] >> tid) & 1ull)) {
                int slot = base0 + __popcll(kept[r] & ((1ull << tid) - 1ull));
                keepArr[slot] = cidx[p];
            }
            base0 += __popcll(kept[r]);
        }
        if (tid == 0) s_keepCount = base0;
    }
    __syncthreads();

    const int kc = s_keepCount;
    if (tid < TOPK) {
        out[b * TOPK + tid]       = (tid < kc) ? keepArr[tid] : -1;
        out[(B + b) * TOPK + tid] = 0;
    }
}

extern "C" void kernel_launch(void* const* d_in, const int* in_sizes, int n_in,
                              void* d_out, int out_size, void* d_ws, size_t ws_size,
                              hipStream_t stream)
{
    const float* logits = (const float*)d_in[0];   // [B,Q,C] fp32
    const float* seg    = (const float*)d_in[1];   // [B,Q,2] fp32
    int* out = (int*)d_out;                        // [2B, TOPK] int32

    unsigned long long* keys = (unsigned long long*)d_ws;                 // B*Q*8
    int* classes = (int*)((char*)d_ws + (size_t)B * Q * sizeof(unsigned long long));

    score_kernel<<<(B * Q) / 64, 64, 0, stream>>>(logits, keys, classes);
    nms_kernel<<<B, 1024, 0, stream>>>(keys, classes, seg, out);
}